// Round 11
// baseline (1301.788 us; speedup 1.0000x reference)
//
#include <hip/hip_runtime.h>
#include <stdint.h>

typedef uint16_t u16;
typedef u16   u16x4  __attribute__((ext_vector_type(4)));
typedef u16   u16x8  __attribute__((ext_vector_type(8)));
typedef __bf16 bf16x8 __attribute__((ext_vector_type(8)));
typedef float f32x4  __attribute__((ext_vector_type(4)));

#define GRID 1024
#define NBAR 32

__device__ __forceinline__ float b2f(u16 x) {
    union { uint32_t u; float f; } c; c.u = ((uint32_t)x) << 16; return c.f;
}
__device__ __forceinline__ u16 f2b(float f) {
    union { float f; uint32_t u; } c; c.f = f;
    uint32_t r = c.u + 0x7FFFu + ((c.u >> 16) & 1u);
    return (u16)(r >> 16);
}
__device__ __forceinline__ float silu_f(float x) { return x / (1.f + __expf(-x)); }
__device__ __forceinline__ float softplus_f(float x) {
    return fmaxf(x, 0.f) + __logf(1.f + __expf(-fabsf(x)));
}
__device__ __forceinline__ void gload16(const u16* g, u16* l) {
    __builtin_amdgcn_global_load_lds(
        (const __attribute__((address_space(1))) void*)(g),
        (__attribute__((address_space(3))) void*)(l), 16, 0, 0);
}

// device-scope grid barrier (monotonic targets; all GRID blocks resident by
// construction: 36KB LDS -> 4 blocks/CU, launch_bounds(256,4), grid=1024).
__device__ __forceinline__ void gbar(int* bars, int phase) {
    __syncthreads();                    // drains vmcnt -> block stores in L2
    if (threadIdx.x == 0) {
        __threadfence();                // release: L2 -> coherence point
        atomicAdd(&bars[blockIdx.x & (NBAR - 1)], 1);
    }
    if (threadIdx.x < NBAR) {
        const int target = phase * (GRID / NBAR);
        while (atomicAdd(&bars[threadIdx.x], 0) < target)
            __builtin_amdgcn_s_sleep(2);
    }
    __syncthreads();
    __threadfence();                    // acquire: invalidate stale caches
}

struct MegaArgs {
    const void* cs[13];
    u16* cd[13];
    int ccum[14];
    int ctotal;
    const u16* xraw;
    const u16 *cx, *cWin, *ccw, *ccb, *wxp, *cWdt, *cbdt, *cWout, *cAlog, *cD,
              *cWc, *clat;
    u16 *xr, *uu, *yg, *xdbl, *qb, *kb, *vb;
    float *xdbl_part, *sc, *out_part;
    int* bars;
    void* dout;
};

// ---------------- MFMA NT GEMM tile: 128(M) x 64(N), BK=64 ----------------
// 4 waves (2x2), 4x2 subtiles of 16x16x32 bf16, swizzled LDS slots, async
// global_load_lds staging. EPI 0: bf16 store. 2: f32 partial at Cf+bz*zslab.
template<int EPI>
__device__ __forceinline__ void gemm64(
    u16* lsh, int bx, int by, int bz,
    const u16* __restrict__ A, const u16* __restrict__ B,
    int Kc, int lda, int ldb,
    u16* __restrict__ Cb, float* __restrict__ Cf, int ldc, size_t zslab)
{
    u16* lA = lsh;          // 128*64 = 8192 u16
    u16* lB = lsh + 8192;   // 64*64  = 4096 u16
    const int tid  = threadIdx.x;
    const int wave = tid >> 6, lane = tid & 63;
    const int quad = lane >> 4, l16 = lane & 15;
    const int wm = wave & 1, wn = wave >> 1;
    const int row0 = by * 128, col0 = bx * 64;
    const int kbeg = bz * Kc;

    f32x4 acc[4][2];
    const f32x4 zf = {0.f, 0.f, 0.f, 0.f};
    for (int i = 0; i < 4; i++) for (int j = 0; j < 2; j++) acc[i][j] = zf;

    // chunk c: 16B at lX[c*8]; row r=c>>3, slot s=c&7 holds k-group
    // q=(s-(r>>1))&7 (bank swizzle).
    const u16* Ap[4]; const u16* Bp[2];
    int lbaseA[4], lbaseB[2];
    for (int t = 0; t < 4; t++) {
        int c = t * 256 + tid;
        int r = c >> 3, s = c & 7;
        int q = (s - (r >> 1)) & 7;
        Ap[t] = A + (size_t)(row0 + r) * lda + q * 8 + kbeg;
        lbaseA[t] = (t * 256 + wave * 64) * 8;
    }
    for (int t = 0; t < 2; t++) {
        int c = t * 256 + tid;
        int r = c >> 3, s = c & 7;
        int q = (s - (r >> 1)) & 7;
        Bp[t] = B + (size_t)(col0 + r) * ldb + q * 8 + kbeg;
        lbaseB[t] = (t * 256 + wave * 64) * 8;
    }

    for (int k0 = 0; k0 < Kc; k0 += 64) {
        for (int t = 0; t < 4; t++) gload16(Ap[t] + k0, &lA[lbaseA[t]]);
        for (int t = 0; t < 2; t++) gload16(Bp[t] + k0, &lB[lbaseB[t]]);
        __syncthreads();
        for (int half = 0; half < 2; half++) {
            bf16x8 af[4], bfr[2];
            for (int i = 0; i < 4; i++) {
                int r = wm * 64 + i * 16 + l16;
                int s = (half * 4 + quad + (r >> 1)) & 7;
                af[i] = *(const bf16x8*)&lA[r * 64 + s * 8];
            }
            for (int j = 0; j < 2; j++) {
                int r = wn * 32 + j * 16 + l16;
                int s = (half * 4 + quad + (r >> 1)) & 7;
                bfr[j] = *(const bf16x8*)&lB[r * 64 + s * 8];
            }
            for (int i = 0; i < 4; i++)
                for (int j = 0; j < 2; j++)
                    acc[i][j] = __builtin_amdgcn_mfma_f32_16x16x32_bf16(af[i], bfr[j], acc[i][j], 0, 0, 0);
        }
        __syncthreads();
    }

    float* dstf = (EPI == 2) ? (Cf + (size_t)bz * zslab) : Cf;
    for (int i = 0; i < 4; i++) {
        int mb = row0 + wm * 64 + i * 16 + quad * 4;
        for (int j = 0; j < 2; j++) {
            int n = col0 + wn * 32 + j * 16 + l16;
            if (EPI == 0) {
                for (int v = 0; v < 4; v++)
                    Cb[(size_t)(mb + v) * ldc + n] = f2b(acc[i][j][v]);
            } else {
                for (int v = 0; v < 4; v++)
                    dstf[(size_t)(mb + v) * ldc + n] = acc[i][j][v];
            }
        }
    }
}

__global__ __launch_bounds__(256, 4) void mega_k(MegaArgs A)
{
    __shared__ __align__(16) u16 lsh[18432];   // 36 KB -> 4 blocks/CU
    __shared__ int badcnt;
    const int tid = threadIdx.x;
    const int bid = blockIdx.x;
    const int wave = tid >> 6, lane = tid & 63;
    const int quad = lane >> 4, l16 = lane & 15;

    // dtype flag: 1 = f32 inputs, 0 = bf16 (reads first 256 raw words of x)
    if (tid == 0) badcnt = 0;
    __syncthreads();
    { float v = b2f(A.xraw[tid]); if (!(fabsf(v) < 1000.f)) atomicAdd(&badcnt, 1); }
    __syncthreads();
    const int flag = badcnt;

    // ---- P0: canonicalize inputs to bf16 ----
    for (int u4 = bid * 256 + tid; u4 < A.ctotal; u4 += GRID * 256) {
        int seg = 0;
        while (u4 >= A.ccum[seg + 1]) seg++;
        int local = u4 - A.ccum[seg];
        const void* s = A.cs[seg];
        u16x4 o;
        if (s == nullptr) {
            o[0] = o[1] = o[2] = o[3] = 0;
        } else if (flag) {
            f32x4 vv = ((const f32x4*)s)[local];
            for (int e = 0; e < 4; e++) o[e] = f2b(vv[e]);
        } else {
            o = ((const u16x4*)s)[local];
        }
        *(u16x4*)(A.cd[seg] + (size_t)local * 4) = o;
    }
    gbar(A.bars, 1);

    // ---- P1: xr = x @ W_in^T (M=2048,N=4096,K=1024), 1024 tiles 1:1 ----
    gemm64<0>(lsh, bid & 63, bid >> 6, 0, A.cx, A.cWin, 1024, 1024, 1024,
              A.xr, nullptr, 4096, 0);
    gbar(A.bars, 2);

    // ---- P2: depthwise causal conv(4) + bias + SiLU ----
    for (int vb = bid; vb < 2048; vb += GRID) {
        int l  = vb & 1023;
        int d0 = tid * 8;
        float acc[8];
        u16x8 bias = *(const u16x8*)&A.ccb[d0];
        for (int j = 0; j < 8; j++) acc[j] = b2f(bias[j]);
        union { u16x8 v[4]; u16 s[32]; } wb;
        for (int t = 0; t < 4; t++) wb.v[t] = *(const u16x8*)&A.ccw[d0 * 4 + t * 8];
        for (int t = 0; t < 4; t++) {
            int ls = l - 3 + t;
            if (ls < 0) continue;
            u16x8 xv = *(const u16x8*)&A.xr[(size_t)(vb - 3 + t) * 4096 + d0];
            for (int j = 0; j < 8; j++) acc[j] += b2f(xv[j]) * b2f(wb.s[j * 4 + t]);
        }
        u16x8 o;
        for (int j = 0; j < 8; j++) o[j] = f2b(silu_f(acc[j]));
        *(u16x8*)&A.uu[(size_t)vb * 2048 + d0] = o;
    }
    gbar(A.bars, 3);

    // ---- P3: x_dbl = u @ W_x^T, split-K 16 -> f32 slabs (512 tiles) ----
    if (bid < 512)
        gemm64<2>(lsh, bid & 1, (bid >> 1) & 15, bid >> 5, A.uu, A.wxp,
                  128, 2048, 2048, nullptr, A.xdbl_part, 128, 262144);
    gbar(A.bars, 4);

    // ---- P4: reduce 16 slabs -> xdbl bf16 (2048x128) ----
    if (bid < 256) {
        int idx = (bid * 256 + tid) * 4;
        f32x4 s = {0.f, 0.f, 0.f, 0.f};
        for (int sl = 0; sl < 16; sl++) {
            f32x4 p = *(const f32x4*)&A.xdbl_part[(size_t)sl * 262144 + idx];
            for (int e = 0; e < 4; e++) s[e] += p[e];
        }
        u16x4 o;
        for (int e = 0; e < 4; e++) o[e] = f2b(s[e]);
        *(u16x4*)&A.xdbl[idx] = o;
    }
    gbar(A.bars, 5);

    // ---- P5: scan w/ inline delta-MFMA (0..511) | qkv (512..1007) ----
    if (bid < 512) {
        u16* lA = lsh;                       // xdbl A-tile, then dead
        u16* lB = lsh + 2048;                // Wdt tile, then overlaid by dls
        float* dls = (float*)(lsh + 2048);   // [32][256] f32
        float* Bsf = (float*)lsh;            // overlay lA after MFMA
        float* Csf = Bsf + 512;
        int dblk = bid & 7, bg = bid >> 3;   // bg = b*32+g
        int d = dblk * 256 + tid;

        {   // stage A = xdbl[bg's 32 rows][0:64]
            int r = tid >> 3, s = tid & 7;
            int qg = (s - (r >> 1)) & 7;
            gload16(&A.xdbl[(size_t)(bg * 32 + r) * 128 + qg * 8], &lA[(wave * 64) * 8]);
        }
        for (int t = 0; t < 8; t++) {   // stage B = Wdt rows [dblk*256,+256)
            int c = t * 256 + tid;
            int r = c >> 3, s = c & 7;
            int qg = (s - (r >> 1)) & 7;
            gload16(&A.cWdt[(size_t)(dblk * 256 + r) * 64 + qg * 8],
                    &lB[(t * 256 + wave * 64) * 8]);
        }
        __syncthreads();

        f32x4 dacc[2][4];
        const f32x4 zf = {0.f, 0.f, 0.f, 0.f};
        for (int i = 0; i < 2; i++) for (int j = 0; j < 4; j++) dacc[i][j] = zf;
        for (int half = 0; half < 2; half++) {
            bf16x8 af[2], bfr[4];
            for (int i = 0; i < 2; i++) {
                int r = i * 16 + l16;
                int s = (half * 4 + quad + (r >> 1)) & 7;
                af[i] = *(const bf16x8*)&lA[r * 64 + s * 8];
            }
            for (int j = 0; j < 4; j++) {
                int r = wave * 64 + j * 16 + l16;
                int s = (half * 4 + quad + (r >> 1)) & 7;
                bfr[j] = *(const bf16x8*)&lB[r * 64 + s * 8];
            }
            for (int i = 0; i < 2; i++)
                for (int j = 0; j < 4; j++)
                    dacc[i][j] = __builtin_amdgcn_mfma_f32_16x16x32_bf16(af[i], bfr[j], dacc[i][j], 0, 0, 0);
        }
        __syncthreads();   // all lA/lB reads done before overlays

        for (int j = 0; j < 4; j++) {
            int n = wave * 64 + j * 16 + l16;
            float bv = b2f(A.cbdt[dblk * 256 + n]);
            for (int i = 0; i < 2; i++) {
                int mb = i * 16 + quad * 4;
                for (int vv = 0; vv < 4; vv++)
                    dls[(mb + vv) * 256 + n] = softplus_f(dacc[i][j][vv] + bv);
            }
        }
        for (int idx = tid; idx < 512; idx += 256) {
            int p = idx >> 4, n = idx & 15;
            const u16* xp = &A.xdbl[(size_t)(bg * 32 + p) * 128];
            Bsf[p * 16 + n] = b2f(xp[64 + n]);
            Csf[p * 16 + n] = b2f(xp[80 + n]);
        }
        __syncthreads();

        float a[16], h[16];
        {
            u16x8 a0 = *(const u16x8*)&A.cAlog[(size_t)d * 16];
            u16x8 a1 = *(const u16x8*)&A.cAlog[(size_t)d * 16 + 8];
            u16x8 l0 = *(const u16x8*)&A.clat[((size_t)bg * 2048 + d) * 16];
            u16x8 l1 = *(const u16x8*)&A.clat[((size_t)bg * 2048 + d) * 16 + 8];
            for (int n = 0; n < 8; n++) {
                a[n] = -__expf(b2f(a0[n])); a[8 + n] = -__expf(b2f(a1[n]));
                h[n] = b2f(l0[n]);          h[8 + n] = b2f(l1[n]);
            }
        }
        float Dd = b2f(A.cD[d]);
        for (int p = 0; p < 32; p++) {
            size_t row = (size_t)bg * 32 + p;
            float dlt = dls[p * 256 + tid];
            float uu  = b2f(A.uu[row * 2048 + d]);
            float db  = dlt * uu;
            float y = 0.f;
            if (p == 0) {
                for (int n = 0; n < 16; n++) { h[n] += db * Bsf[n]; y += h[n] * Csf[n]; }
            } else {
                for (int n = 0; n < 16; n++) {
                    float w = __expf(dlt * a[n]);
                    h[n] = w * h[n] + db * Bsf[p * 16 + n];
                    y += h[n] * Csf[p * 16 + n];
                }
            }
            float rs = b2f(A.xr[row * 4096 + 2048 + d]);
            A.yg[row * 2048 + d] = f2b((y + uu * Dd) * silu_f(rs));
        }
    } else if (bid < 1008) {
        float (*Ws)[16] = (float(*)[16])lsh;
        for (int i = tid; i < 768; i += 256) Ws[i >> 4][i & 15] = b2f(A.cWc[i]);
        __syncthreads();
        int gid = (bid - 512) * 256 + tid;           // 126976 total
        int d = gid & 2047;
        int bi = gid >> 11;                          // b*31+i
        int b = bi / 31, i = bi - b * 31;
        const u16* lp = &A.clat[(((size_t)b * 32 + i) * 2048 + d) * 16];
        float lv[16];
        {
            u16x8 l0 = *(const u16x8*)lp, l1 = *(const u16x8*)(lp + 8);
            for (int m = 0; m < 8; m++) { lv[m] = b2f(l0[m]); lv[8 + m] = b2f(l1[m]); }
        }
        u16* outs[3] = {A.qb, A.kb, A.vb};
        for (int pl = 0; pl < 3; pl++) {
            u16x8 o0, o1;
            for (int n = 0; n < 16; n++) {
                float s = 0.f;
                for (int m = 0; m < 16; m++) s += lv[m] * Ws[pl * 16 + n][m];
                if (n < 8) o0[n] = f2b(s); else o1[n - 8] = f2b(s);
            }
            u16* op = outs[pl] + (size_t)bi * 32768 + d * 16;
            *(u16x8*)op = o0; *(u16x8*)(op + 8) = o1;
        }
    }
    gbar(A.bars, 6);

    // ---- P6: out-GEMM split-K2 (vb 0..511) | scores (512..2433) ----
    for (int vb = bid; vb < 2434; vb += GRID) {
        if (vb < 512) {
            gemm64<2>(lsh, vb & 15, (vb >> 4) & 15, vb >> 8, A.yg, A.cWout,
                      1024, 2048, 2048, nullptr, A.out_part, 1024,
                      (size_t)2048 * 1024);
        } else {
            int idx = vb - 512;              // b*961 + i*31 + j
            int b = idx / 961, r = idx - b * 961;
            int i = r / 31, j = r - i * 31;
            if (j <= i) {
                const u16* qp = A.qb + ((size_t)b * 31 + i) * 32768;
                const u16* kp = A.kb + ((size_t)b * 31 + j) * 32768;
                float s = 0.f;
                for (int t = tid * 8; t < 32768; t += 2048) {
                    u16x8 aa = *(const u16x8*)&qp[t];
                    u16x8 cc = *(const u16x8*)&kp[t];
                    for (int e = 0; e < 8; e++) s += b2f(aa[e]) * b2f(cc[e]);
                }
                for (int off = 32; off; off >>= 1) s += __shfl_xor(s, off);
                float* red = (float*)lsh;
                if ((tid & 63) == 0) red[tid >> 6] = s;
                __syncthreads();
                if (tid == 0)
                    A.sc[idx] = (red[0] + red[1] + red[2] + red[3]) * 5.5242717e-3f;
                __syncthreads();   // lsh reuse guard
            }
        }
    }
    gbar(A.bars, 7);

    // ---- P7: attv+softmax (vb 0..1023) -> dout latent | redout (1024..3071) ----
    for (int vb = bid; vb < 3072; vb += GRID) {
        if (vb < 1024) {
            int chunk = vb & 15, bi = vb >> 4;
            int b = bi >> 5, i = (bi & 31) - 1;   // i = -1 -> zero row (group 0)
            float* as = (float*)lsh;
            if (i >= 0 && tid < 64) {
                float x = (tid <= i) ? A.sc[(size_t)b * 961 + i * 31 + tid] : -3.4e38f;
                float mx = x;
                for (int off = 32; off; off >>= 1) mx = fmaxf(mx, __shfl_xor(mx, off));
                float e = (tid <= i) ? __expf(x - mx) : 0.f;
                float sm = e;
                for (int off = 32; off; off >>= 1) sm += __shfl_xor(sm, off);
                if (tid < 32) as[tid] = e / sm;
            }
            __syncthreads();
            int dn = chunk * 2048 + tid * 8;
            float acc[8] = {0, 0, 0, 0, 0, 0, 0, 0};
            if (i >= 0) {
                for (int j = 0; j <= i; j++) {
                    u16x8 vv = *(const u16x8*)&A.vb[((size_t)b * 31 + j) * 32768 + dn];
                    float aj = as[j];
                    for (int e = 0; e < 8; e++) acc[e] += aj * b2f(vv[e]);
                }
                for (int e = 0; e < 8; e++) if (!(fabsf(acc[e]) < 1e30f)) acc[e] = 0.f;
            }
            size_t ofs = 2097152 + ((size_t)b * 32 + (i + 1)) * 32768 + dn;
            if (flag) {
                f32x4 o0, o1;
                for (int e = 0; e < 4; e++) { o0[e] = acc[e]; o1[e] = acc[4 + e]; }
                *(f32x4*)((float*)A.dout + ofs) = o0;
                *(f32x4*)((float*)A.dout + ofs + 4) = o1;
            } else {
                u16x8 o;
                for (int e = 0; e < 8; e++) o[e] = f2b(acc[e]);
                *(u16x8*)((u16*)A.dout + ofs) = o;
            }
            __syncthreads();   // lsh reuse guard
        } else {
            int gid = (vb - 1024) * 256 + tid;   // 524288 total
            int m = gid >> 8;
            int j = (gid & 255) * 4;
            f32x4 s = {0.f, 0.f, 0.f, 0.f};
            for (int ks = 0; ks < 2; ks++) {
                f32x4 p = *(const f32x4*)&A.out_part[((size_t)ks * 2048 + m) * 1024 + j];
                for (int e = 0; e < 4; e++) s[e] += p[e];
            }
            for (int e = 0; e < 4; e++) if (!(fabsf(s[e]) < 1e30f)) s[e] = 0.f;
            if (flag) {
                ((f32x4*)A.dout)[(size_t)m * 256 + (j >> 2)] = s;
            } else {
                u16x4 o;
                for (int e = 0; e < 4; e++) o[e] = f2b(s[e]);
                ((u16x4*)A.dout)[(size_t)m * 256 + (j >> 2)] = o;
            }
        }
    }
}

extern "C" void kernel_launch(void* const* d_in, const int* in_sizes, int n_in,
                              void* d_out, int out_size, void* d_ws, size_t ws_size,
                              hipStream_t stream)
{
    char* ws = (char*)d_ws;
    MegaArgs A;
    A.xraw = (const u16*)d_in[0];
    // canonical bf16 inputs
    u16* cx    = (u16*)(ws + 0);
    u16* clat  = (u16*)(ws + 4194304);
    u16* cWin  = (u16*)(ws + 8388608);
    u16* ccw   = (u16*)(ws + 16777216);
    u16* ccb   = (u16*)(ws + 16793600);
    u16* wxp   = (u16*)(ws + 16797696);   // 128x2048 (W_x + zero pad)
    u16* cWdt  = (u16*)(ws + 17321984);
    u16* cbdt  = (u16*)(ws + 17584128);
    u16* cWout = (u16*)(ws + 17588224);
    u16* cAlog = (u16*)(ws + 21782528);
    u16* cD    = (u16*)(ws + 21848064);
    u16* cWc   = (u16*)(ws + 21852160);
    A.cx = cx; A.clat = clat; A.cWin = cWin; A.ccw = ccw; A.ccb = ccb;
    A.wxp = wxp; A.cWdt = cWdt; A.cbdt = cbdt; A.cWout = cWout;
    A.cAlog = cAlog; A.cD = cD; A.cWc = cWc;
    // intermediates
    A.xdbl_part = (float*)(ws + 21853760);  // 16 x 2048x128 f32 slabs
    A.xdbl      = (u16*)(ws + 38630976);    // 2048x128 bf16
    A.sc        = (float*)(ws + 39155264);  // 1922 f32
    A.uu        = (u16*)(ws + 39163008);    // 2048x2048 bf16
    A.xr        = (u16*)(ws + 47551616);    // 2048x4096 bf16
    A.yg        = (u16*)(ws + 64328832);    // 2048x2048 bf16
    A.qb        = (u16*)(ws + 72717440);    // 3x 2031616 bf16
    A.kb        = A.qb + 2031616;
    A.vb        = A.kb + 2031616;
    A.out_part  = (float*)(ws + 84907136);  // 2x2048x1024 f32
    A.bars      = (int*)(ws + 101684352);   // 32 ints
    A.dout      = d_out;

    const void* srcs[13] = { d_in[0], d_in[1], d_in[2], d_in[3], d_in[4],
                             d_in[5], nullptr, d_in[6], d_in[7], d_in[8],
                             d_in[9], d_in[10], d_in[11] };
    u16* dsts[13] = { cx, clat, cWin, ccw, ccb,
                      wxp, wxp + 196608, cWdt, cbdt, cWout,
                      cAlog, cD, cWc };
    int ns[13] = { 2097152, 2097152, 4194304, 8192, 2048,
                   196608, 65536, 131072, 2048, 2097152,
                   32768, 2048, 768 };
    int cum = 0;
    for (int i = 0; i < 13; i++) {
        A.cs[i] = srcs[i]; A.cd[i] = dsts[i];
        A.ccum[i] = cum; cum += ns[i] / 4;
    }
    A.ccum[13] = cum; A.ctotal = cum;    // 2,731,712 units

    hipMemsetAsync(A.bars, 0, NBAR * sizeof(int), stream);
    mega_k<<<GRID, 256, 0, stream>>>(A);
}